// Round 1
// baseline (79.595 us; speedup 1.0000x reference)
//
#include <hip/hip_runtime.h>

// ExpertParallel dispatch+combine collapses to an exact identity permutation:
//   out[n, k, :] = x[n, :]  for k in {0, 1}
// (gather by sort_indices then scatter back by sort_indices cancel bit-exactly).
// So the kernel is a pure broadcast copy: read 128 MB, write 256 MB.

constexpr int N_TOKENS = 8192;
constexpr int HIDDEN   = 4096;
constexpr int TOPK     = 2;
constexpr int H4       = HIDDEN / 4;  // float4 per row = 1024

__global__ void ExpertParallel_63711544868877_kernel(const float4* __restrict__ x4,
                                                     float4* __restrict__ out4,
                                                     int total /* = N_TOKENS * H4 */) {
    int idx    = blockIdx.x * blockDim.x + threadIdx.x;
    int stride = gridDim.x * blockDim.x;
    for (int i = idx; i < total; i += stride) {
        int n = i >> 10;          // i / H4   (H4 == 1024)
        int c = i & (H4 - 1);     // i % H4
        float4 v = x4[i];
        float4* o = out4 + (size_t)n * (TOPK * H4) + c;
        o[0]  = v;                // k = 0
        o[H4] = v;                // k = 1
    }
}

extern "C" void kernel_launch(void* const* d_in, const int* in_sizes, int n_in,
                              void* d_out, int out_size, void* d_ws, size_t ws_size,
                              hipStream_t stream) {
    const float4* x4  = (const float4*)d_in[0];  // x: [8192, 4096] f32
    // d_in[1] = expert_indices (unused: permutation cancels)
    // d_in[2] = ep_world_size  (unused)
    float4* out4 = (float4*)d_out;               // [8192, 2, 4096] f32

    const int total = N_TOKENS * H4;             // 8,388,608 float4 reads
    const int block = 256;
    const int grid  = 2048;                      // grid-stride covers the rest
    ExpertParallel_63711544868877_kernel<<<grid, block, 0, stream>>>(x4, out4, total);
}